// Round 5
// baseline (163.957 us; speedup 1.0000x reference)
//
#include <hip/hip_runtime.h>
#include <hip/hip_bf16.h>

#define DIM 1024
#define NHEADS 16
#define HD 64
#define BB 2
#define SS 2048
#define MTOT (BB*SS)      // 4096
#define SCALE 0.125f      // HD^-0.5
#define QSCALE 0.1803368801111204f   // SCALE * log2(e): scores land in exp2 domain

typedef __attribute__((ext_vector_type(8))) short bf16x8;   // 8 bf16 = 4 VGPRs
typedef __attribute__((ext_vector_type(4))) float f32x4;

__device__ __forceinline__ float bf2f(short u) {
  union { float f; unsigned int i; } v;
  v.i = ((unsigned int)(unsigned short)u) << 16;
  return v.f;
}
__device__ __forceinline__ short f2bf(float f) {
  union { float f; unsigned int i; } v; v.f = f;
  unsigned int r = v.i + 0x7fffu + ((v.i >> 16) & 1u);   // RNE
  return (short)(r >> 16);
}
__device__ __forceinline__ unsigned int cvtpk_bf16(float lo, float hi) {
  unsigned int r;
  asm("v_cvt_pk_bf16_f32 %0, %1, %2" : "=v"(r) : "v"(lo), "v"(hi));
  return r;
}
// async global->LDS, 16B per lane; LDS dest = wave-uniform base + lane*16 (m97/m104)
__device__ __forceinline__ void async_load16(const short* g, short* l) {
  __builtin_amdgcn_global_load_lds(
      (const __attribute__((address_space(1))) unsigned int*)g,
      (__attribute__((address_space(3))) unsigned int*)l, 16, 0, 0);
}

// ---------------- fp32 -> bf16 ----------------
__global__ void cvt_kernel(const float* __restrict__ in, short* __restrict__ out, int n) {
  int nq = n >> 2;
  int stride = gridDim.x * blockDim.x;
  for (int q = blockIdx.x * blockDim.x + threadIdx.x; q < nq; q += stride) {
    float4 v = *(const float4*)(in + (size_t)q * 4);
    short4 o;
    o.x = f2bf(v.x); o.y = f2bf(v.y); o.z = f2bf(v.z); o.w = f2bf(v.w);
    *(short4*)(out + (size_t)q * 4) = o;
  }
}

// ---------------- RoPE cos/sin table (S x 32, fp32) ----------------
__global__ void rope_table_kernel(float* __restrict__ ct, float* __restrict__ st) {
  int i = blockIdx.x * blockDim.x + threadIdx.x;
  if (i >= SS * 32) return;
  int s = i >> 5, j = i & 31;
  float inv = 1.0f / powf(10000.0f, (float)(2 * j) / 64.0f);
  float ang = (float)s * inv;
  ct[i] = cosf(ang);
  st[i] = sinf(ang);
}

// ---------------- GEMM: C[m][n] = sum_k A[m][k] * B[n][k]  (both row-major, K-contig) ----------------
// 128x128 tile, 4 waves (2x2), BK=32. Staging via global_load_lds width=16 into LINEAR
// [128][32] LDS (m97 lever): wave-uniform LDS base + lane*16B; per-lane global src.
// Frag reads at [r][grp*8]: bank-group (16r+4g)%32 -> 8 groups x 8 lanes, even (conflict-free).
template<bool OUT_F32>
__global__ __launch_bounds__(256) void gemm_bt(
    const short* __restrict__ A, const short* __restrict__ B,
    void* __restrict__ C, int M, int N, int K) {
  __shared__ __align__(16) short As[128][32];
  __shared__ __align__(16) short Bs[128][32];
  const int tid = threadIdx.x;
  const int lane = tid & 63;
  const int wid = tid >> 6;
  const int wm = (wid >> 1) * 64, wn = (wid & 1) * 64;
  const int m0 = blockIdx.y * 128, n0 = blockIdx.x * 128;
  const int row = lane & 15, kg = (lane >> 4) * 8;
  const int lrow = lane >> 2;          // 0..15 within a 16-row chunk
  const int lcol = (lane & 3) * 8;     // 0,8,16,24 shorts

  f32x4 acc[4][4];
#pragma unroll
  for (int m = 0; m < 4; m++)
#pragma unroll
    for (int n = 0; n < 4; n++) acc[m][n] = (f32x4){0.f, 0.f, 0.f, 0.f};

  for (int kk = 0; kk < K; kk += 32) {
    __syncthreads();                   // previous tile fully consumed
#pragma unroll
    for (int i = 0; i < 2; i++) {
      int base = i * 64 + wid * 16;    // 16-row chunk staged by this wave
      async_load16(A + (size_t)(m0 + base + lrow) * K + kk + lcol, &As[base][0]);
      async_load16(B + (size_t)(n0 + base + lrow) * K + kk + lcol, &Bs[base][0]);
    }
    __syncthreads();                   // compiler drains vmcnt before barrier -> tiles ready
    bf16x8 af[4], bfr[4];
#pragma unroll
    for (int m = 0; m < 4; m++) af[m] = *(const bf16x8*)(&As[wm + m * 16 + row][kg]);
#pragma unroll
    for (int n = 0; n < 4; n++) bfr[n] = *(const bf16x8*)(&Bs[wn + n * 16 + row][kg]);
#pragma unroll
    for (int m = 0; m < 4; m++)
#pragma unroll
      for (int n = 0; n < 4; n++)
        acc[m][n] = __builtin_amdgcn_mfma_f32_16x16x32_bf16(af[m], bfr[n], acc[m][n], 0, 0, 0);
  }
  const int orow = (lane >> 4) * 4, ocol = lane & 15;
#pragma unroll
  for (int m = 0; m < 4; m++)
#pragma unroll
    for (int n = 0; n < 4; n++)
#pragma unroll
      for (int r = 0; r < 4; r++) {
        int gr = m0 + wm + m * 16 + orow + r;
        int gc = n0 + wn + n * 16 + ocol;
        if (OUT_F32) ((float*)C)[(size_t)gr * N + gc] = acc[m][n][r];
        else         ((short*)C)[(size_t)gr * N + gc] = f2bf(acc[m][n][r]);
      }
}

// ---------------- RoPE on Q,K + layout (B,S,3,H,hd) -> (BH,S,hd) ----------------
__global__ __launch_bounds__(256) void rope_kernel(
    const short* __restrict__ qkv, const float* __restrict__ ct, const float* __restrict__ st,
    short* __restrict__ Q, short* __restrict__ K) {
  int bh = blockIdx.y;
  int b = bh >> 4, h = bh & 15;
  int s0 = blockIdx.x * 64;
  int t = threadIdx.x;
  int rl = t >> 2;
  int d8 = (t & 3) * 8;
  int s = s0 + rl;
  size_t inbase = ((size_t)(b * SS + s)) * 3072 + h * 64 + d8;
  size_t outbase = ((size_t)bh * SS + s) * 64 + d8;
  float c[8], sn[8];
#pragma unroll
  for (int j = 0; j < 8; j++) { c[j] = ct[s * 32 + d8 + j]; sn[j] = st[s * 32 + d8 + j]; }
  {
    bf16x8 x1 = *(const bf16x8*)(qkv + inbase);
    bf16x8 x2 = *(const bf16x8*)(qkv + inbase + 32);
    bf16x8 o1, o2;
#pragma unroll
    for (int j = 0; j < 8; j++) {
      float a = bf2f(x1[j]), bb = bf2f(x2[j]);
      o1[j] = f2bf((a * c[j] - bb * sn[j]) * QSCALE);
      o2[j] = f2bf((bb * c[j] + a * sn[j]) * QSCALE);
    }
    *(bf16x8*)(Q + outbase) = o1;
    *(bf16x8*)(Q + outbase + 32) = o2;
  }
  {
    bf16x8 x1 = *(const bf16x8*)(qkv + inbase + 1024);
    bf16x8 x2 = *(const bf16x8*)(qkv + inbase + 1024 + 32);
    bf16x8 o1, o2;
#pragma unroll
    for (int j = 0; j < 8; j++) {
      float a = bf2f(x1[j]), bb = bf2f(x2[j]);
      o1[j] = f2bf(a * c[j] - bb * sn[j]);
      o2[j] = f2bf(bb * c[j] + a * sn[j]);
    }
    *(bf16x8*)(K + outbase) = o1;
    *(bf16x8*)(K + outbase + 32) = o2;
  }
}

// ---------------- V: (B,S,3,H,hd) -> Vt (BH, hd, S) transposed AND slot-permuted ----------------
// Within each 64-kv block, position p = c*32 + g*8 + 4*hi + lo holds kv = c*32 + hi*16 + g*4 + lo,
// so the attn PV A-fragment is one contiguous b128 read at [d][c*32 + g*8].
__global__ __launch_bounds__(256) void vtrans_kernel(const short* __restrict__ qkv, short* __restrict__ Vt) {
  __shared__ short ls[64][72];
  int bh = blockIdx.y, b = bh >> 4, h = bh & 15;
  int s0 = blockIdx.x * 64;
  int t = threadIdx.x;
#pragma unroll
  for (int p = 0; p < 2; p++) {
    int idx = p * 256 + t;
    int r = idx >> 3, c8 = (idx & 7) * 8;
    *(bf16x8*)(&ls[r][c8]) =
        *(const bf16x8*)(qkv + ((size_t)(b * SS + s0 + r)) * 3072 + 2048 + h * 64 + c8);
  }
  __syncthreads();
  int dl = t >> 2, sg = (t & 3) * 16;       // this thread: 16 consecutive kv = sg..sg+15
  int c = sg >> 5, hi = (sg >> 4) & 1;
  short tmp[16];
#pragma unroll
  for (int j = 0; j < 16; j++) tmp[j] = ls[sg + j][dl];
  size_t rowbase = ((size_t)bh * 64 + dl) * SS + s0;
#pragma unroll
  for (int g = 0; g < 4; g++) {
    short4 o = { tmp[4 * g], tmp[4 * g + 1], tmp[4 * g + 2], tmp[4 * g + 3] };
    *(short4*)(Vt + rowbase + c * 32 + g * 8 + hi * 4) = o;
  }
}

// ---------------- Flash attention, causal. QBLK=32, 2 waves, 2048 blocks (8/CU) ----------------
// Swapped-operand: S^T = mfma(K,Q), lane owns one q-row (scalar m,l; P in regs).
// Round-4 diagnosis: latency-bound at 18.7% occupancy (grid 1024 = 4 blk/CU + causal
// imbalance). Fix: halve block q-range -> 2048 blocks = exactly 8/CU, finer imbalance.
__global__ __launch_bounds__(128) void attn_kernel(
    const short* __restrict__ Qp, const short* __restrict__ Kp, const short* __restrict__ Vt,
    short* __restrict__ O) {
  __shared__ short Ks[64][72];        // [kv][d]
  __shared__ short Vs[64][72];        // [d][permuted kv]
  int flat = blockIdx.x;
  int wk = (flat & 7) * 256 + (flat >> 3);   // XCD-chunked swizzle: 4 bh per XCD (2048%8==0)
  int bh = wk >> 6;
  int qi = 63 - (wk & 63);                   // heavy q-tiles first within each chunk
  int b = bh >> 4, h = bh & 15;
  int q0 = qi * 32;
  int tid = threadIdx.x, lane = tid & 63, w = tid >> 6;   // w in {0,1}
  int row = lane & 15, grp = lane >> 4;
  int q = q0 + w * 16 + row;                 // this lane's q row

  bf16x8 qf0, qf1;
  {
    size_t qb = ((size_t)bh * SS + q) * 64 + grp * 8;
    qf0 = *(const bf16x8*)(Qp + qb);
    qf1 = *(const bf16x8*)(Qp + qb + 32);
  }
  f32x4 acc[4];
#pragma unroll
  for (int d = 0; d < 4; d++) acc[d] = (f32x4){0.f, 0.f, 0.f, 0.f};
  float m = -1e30f, l = 0.f;

  const int ksr = tid >> 3;            // 0..15
  const int ksc = (tid & 7) * 8;
  const short* Kbase = Kp + (size_t)bh * SS * 64;
  const short* Vbase = Vt + (size_t)bh * 64 * SS;

  const int ktlast = qi >> 1;          // last 64-kv tile index
  const int d16 = (qi & 1) * 2;        // (q0 - ktlast*64)/16

  for (int kt = 0; kt <= ktlast; kt++) {
    int kv0 = kt * 64;
    __syncthreads();
#pragma unroll
    for (int p2 = 0; p2 < 4; p2++) {
      int r = p2 * 16 + ksr;
      *(bf16x8*)(&Ks[r][ksc]) = *(const bf16x8*)(Kbase + (size_t)(kv0 + r) * 64 + ksc);
      *(bf16x8*)(&Vs[r][ksc]) = *(const bf16x8*)(Vbase + (size_t)r * SS + kv0 + ksc);
    }
    __syncthreads();
    bool last = (kt == ktlast);
    float sv[4][4];
#pragma unroll
    for (int n = 0; n < 4; n++) {
      if (last && n > d16 + w) {             // kv block fully above diagonal for this wave
#pragma unroll
        for (int r = 0; r < 4; r++) sv[n][r] = -1e30f;
        continue;
      }
      f32x4 sf = (f32x4){0.f, 0.f, 0.f, 0.f};
      bf16x8 kf0 = *(const bf16x8*)(&Ks[n * 16 + row][grp * 8]);
      bf16x8 kf1 = *(const bf16x8*)(&Ks[n * 16 + row][grp * 8 + 32]);
      sf = __builtin_amdgcn_mfma_f32_16x16x32_bf16(kf0, qf0, sf, 0, 0, 0);
      sf = __builtin_amdgcn_mfma_f32_16x16x32_bf16(kf1, qf1, sf, 0, 0, 0);
#pragma unroll
      for (int r = 0; r < 4; r++) sv[n][r] = sf[r];      // already exp2-domain (QSCALE folded)
    }
    if (last) {                              // element mask only on the diagonal tile
#pragma unroll
      for (int n = 0; n < 4; n++)
#pragma unroll
        for (int r = 0; r < 4; r++) {
          int kv = kv0 + n * 16 + grp * 4 + r;
          if (kv > q) sv[n][r] = -1e30f;
        }
    }
    float pmax = -1e30f;
#pragma unroll
    for (int n = 0; n < 4; n++)
#pragma unroll
      for (int r = 0; r < 4; r++) pmax = fmaxf(pmax, sv[n][r]);
    pmax = fmaxf(pmax, __shfl_xor(pmax, 16));
    pmax = fmaxf(pmax, __shfl_xor(pmax, 32));
    float mnew = fmaxf(m, pmax);
    float resc = __builtin_amdgcn_exp2f(m - mnew);
    m = mnew;
    float p[4][4];
    float psum = 0.f;
#pragma unroll
    for (int n = 0; n < 4; n++)
#pragma unroll
      for (int r = 0; r < 4; r++) {
        p[n][r] = __builtin_amdgcn_exp2f(sv[n][r] - m);
        psum += p[n][r];
      }
    psum += __shfl_xor(psum, 16);
    psum += __shfl_xor(psum, 32);
    l = l * resc + psum;
#pragma unroll
    for (int d = 0; d < 4; d++)
#pragma unroll
      for (int r = 0; r < 4; r++) acc[d][r] *= resc;
    // PV: O^T = mfma(V^T_frag, P_frag); slot j -> kv = c*32 + 16*(j>>2) + grp*4 + (j&3) both sides
#pragma unroll
    for (int c = 0; c < 2; c++) {
      union { unsigned int u[4]; bf16x8 v; } pu;
      pu.u[0] = cvtpk_bf16(p[2 * c][0], p[2 * c][1]);
      pu.u[1] = cvtpk_bf16(p[2 * c][2], p[2 * c][3]);
      pu.u[2] = cvtpk_bf16(p[2 * c + 1][0], p[2 * c + 1][1]);
      pu.u[3] = cvtpk_bf16(p[2 * c + 1][2], p[2 * c + 1][3]);
#pragma unroll
      for (int dm = 0; dm < 4; dm++) {
        bf16x8 vf = *(const bf16x8*)(&Vs[dm * 16 + row][c * 32 + grp * 8]);   // permuted: b128, conflict-free
        acc[dm] = __builtin_amdgcn_mfma_f32_16x16x32_bf16(vf, pu.v, acc[dm], 0, 0, 0);
      }
    }
  }
  // epilogue: lane holds q = q0+w*16+(lane&15), d = dm*16+grp*4+r
  float linv = 1.0f / l;
  size_t ob = ((size_t)(b * SS + q)) * 1024 + h * 64 + grp * 4;
#pragma unroll
  for (int dm = 0; dm < 4; dm++) {
    union { unsigned int u[2]; short4 s; } ou;
    ou.u[0] = cvtpk_bf16(acc[dm][0] * linv, acc[dm][1] * linv);
    ou.u[1] = cvtpk_bf16(acc[dm][2] * linv, acc[dm][3] * linv);
    *(short4*)(O + ob + dm * 16) = ou.s;
  }
}

extern "C" void kernel_launch(void* const* d_in, const int* in_sizes, int n_in,
                              void* d_out, int out_size, void* d_ws, size_t ws_size,
                              hipStream_t stream) {
  (void)in_sizes; (void)n_in; (void)out_size; (void)ws_size;
  const float* x     = (const float*)d_in[0];
  const float* w_qkv = (const float*)d_in[1];
  const float* w_out = (const float*)d_in[2];
  float* out = (float*)d_out;

  char* ws = (char*)d_ws;
  size_t off = 0;
  auto alloc = [&](size_t bytes) -> void* {
    void* p = ws + off;
    off += (bytes + 255) & ~(size_t)255;
    return p;
  };
  short* xb    = (short*)alloc((size_t)MTOT * DIM * 2);      // dead after GEMM1
  short* wqkvb = (short*)alloc((size_t)3072 * 1024 * 2);
  short* woutb = (short*)alloc((size_t)1024 * 1024 * 2);
  short* qkvb  = (short*)alloc((size_t)MTOT * 3072 * 2);
  short* Qb    = (short*)alloc((size_t)32 * SS * 64 * 2);
  short* Kb    = (short*)alloc((size_t)32 * SS * 64 * 2);
  short* Vtb   = (short*)alloc((size_t)32 * 64 * SS * 2);
  float* ct    = (float*)alloc((size_t)SS * 32 * 4);
  float* st    = (float*)alloc((size_t)SS * 32 * 4);
  short* attnb = xb;   // reuse: xb's last read is GEMM1, attnb written after (stream-ordered)

  cvt_kernel<<<2048, 256, 0, stream>>>(x, xb, MTOT * DIM);
  cvt_kernel<<<2048, 256, 0, stream>>>(w_qkv, wqkvb, 3072 * 1024);
  cvt_kernel<<<1024, 256, 0, stream>>>(w_out, woutb, 1024 * 1024);
  rope_table_kernel<<<SS * 32 / 256, 256, 0, stream>>>(ct, st);
  gemm_bt<false><<<dim3(3072 / 128, MTOT / 128), 256, 0, stream>>>(xb, wqkvb, qkvb, MTOT, 3072, 1024);
  rope_kernel<<<dim3(SS / 64, 32), 256, 0, stream>>>(qkvb, ct, st, Qb, Kb);
  vtrans_kernel<<<dim3(SS / 64, 32), 256, 0, stream>>>(qkvb, Vtb);
  attn_kernel<<<2048, 128, 0, stream>>>(Qb, Kb, Vtb, attnb);
  gemm_bt<true><<<dim3(1024 / 128, MTOT / 128), 256, 0, stream>>>(attnb, woutb, out, MTOT, 1024, 1024);
}

// Round 6
// 137.199 us; speedup vs baseline: 1.1950x; 1.1950x over previous
//
#include <hip/hip_runtime.h>
#include <hip/hip_bf16.h>

#define DIM 1024
#define NHEADS 16
#define HD 64
#define BB 2
#define SS 2048
#define MTOT (BB*SS)      // 4096
#define SCALE 0.125f      // HD^-0.5
#define QSCALE 0.1803368801111204f   // SCALE * log2(e): scores land in exp2 domain

typedef __attribute__((ext_vector_type(8))) short bf16x8;   // 8 bf16 = 4 VGPRs
typedef __attribute__((ext_vector_type(4))) float f32x4;

__device__ __forceinline__ float bf2f(short u) {
  union { float f; unsigned int i; } v;
  v.i = ((unsigned int)(unsigned short)u) << 16;
  return v.f;
}
__device__ __forceinline__ short f2bf(float f) {
  union { float f; unsigned int i; } v; v.f = f;
  unsigned int r = v.i + 0x7fffu + ((v.i >> 16) & 1u);   // RNE
  return (short)(r >> 16);
}
__device__ __forceinline__ unsigned int cvtpk_bf16(float lo, float hi) {
  unsigned int r;
  asm("v_cvt_pk_bf16_f32 %0, %1, %2" : "=v"(r) : "v"(lo), "v"(hi));
  return r;
}
// async global->LDS, 16B per lane; LDS dest = wave-uniform base + lane*16 (m97/m104)
__device__ __forceinline__ void async_load16(const short* g, short* l) {
  __builtin_amdgcn_global_load_lds(
      (const __attribute__((address_space(1))) unsigned int*)g,
      (__attribute__((address_space(3))) unsigned int*)l, 16, 0, 0);
}

// ---------------- fused fp32 -> bf16 for x, w_qkv, w_out (one launch) ----------------
__global__ void cvt3_kernel(const float* __restrict__ a, short* __restrict__ oa, int na,
                            const float* __restrict__ b, short* __restrict__ ob, int nb,
                            const float* __restrict__ c, short* __restrict__ oc, int nc) {
  int stride = gridDim.x * blockDim.x;
  int tot = na + nb + nc;            // quad counts
  for (int q = blockIdx.x * blockDim.x + threadIdx.x; q < tot; q += stride) {
    const float* src; short* dst; int off;
    if (q < na)            { src = a; dst = oa; off = q; }
    else if (q < na + nb)  { src = b; dst = ob; off = q - na; }
    else                   { src = c; dst = oc; off = q - na - nb; }
    float4 v = *(const float4*)(src + (size_t)off * 4);
    short4 o;
    o.x = f2bf(v.x); o.y = f2bf(v.y); o.z = f2bf(v.z); o.w = f2bf(v.w);
    *(short4*)(dst + (size_t)off * 4) = o;
  }
}

// ---------------- RoPE cos/sin table (S x 32, fp32) ----------------
__global__ void rope_table_kernel(float* __restrict__ ct, float* __restrict__ st) {
  int i = blockIdx.x * blockDim.x + threadIdx.x;
  if (i >= SS * 32) return;
  int s = i >> 5, j = i & 31;
  float inv = 1.0f / powf(10000.0f, (float)(2 * j) / 64.0f);
  float ang = (float)s * inv;
  ct[i] = cosf(ang);
  st[i] = sinf(ang);
}

// ---------------- GEMM: C[m][n] = sum_k A[m][k] * B[n][k]  (both row-major, K-contig) ----------------
// 128x128 tile, 4 waves, BK=32, global_load_lds width=16 into linear [128][32] LDS.
// 1D grid with bijective XCD chunking (nwg%8==0): consecutive wg share the A panel.
template<bool OUT_F32>
__global__ __launch_bounds__(256) void gemm_bt(
    const short* __restrict__ A, const short* __restrict__ B,
    void* __restrict__ C, int M, int N, int K) {
  __shared__ __align__(16) short As[128][32];
  __shared__ __align__(16) short Bs[128][32];
  const int nbx = N >> 7;
  const int chunk = gridDim.x >> 3;
  const int wg = (blockIdx.x & 7) * chunk + (blockIdx.x >> 3);
  const int m0 = (wg / nbx) * 128, n0 = (wg % nbx) * 128;
  const int tid = threadIdx.x;
  const int lane = tid & 63;
  const int wid = tid >> 6;
  const int wm = (wid >> 1) * 64, wn = (wid & 1) * 64;
  const int row = lane & 15, kg = (lane >> 4) * 8;
  const int lrow = lane >> 2;          // 0..15 within a 16-row chunk
  const int lcol = (lane & 3) * 8;     // 0,8,16,24 shorts

  f32x4 acc[4][4];
#pragma unroll
  for (int m = 0; m < 4; m++)
#pragma unroll
    for (int n = 0; n < 4; n++) acc[m][n] = (f32x4){0.f, 0.f, 0.f, 0.f};

  for (int kk = 0; kk < K; kk += 32) {
    __syncthreads();                   // previous tile fully consumed
#pragma unroll
    for (int i = 0; i < 2; i++) {
      int base = i * 64 + wid * 16;    // 16-row chunk staged by this wave
      async_load16(A + (size_t)(m0 + base + lrow) * K + kk + lcol, &As[base][0]);
      async_load16(B + (size_t)(n0 + base + lrow) * K + kk + lcol, &Bs[base][0]);
    }
    __syncthreads();                   // vmcnt drained -> tiles ready
    bf16x8 af[4], bfr[4];
#pragma unroll
    for (int m = 0; m < 4; m++) af[m] = *(const bf16x8*)(&As[wm + m * 16 + row][kg]);
#pragma unroll
    for (int n = 0; n < 4; n++) bfr[n] = *(const bf16x8*)(&Bs[wn + n * 16 + row][kg]);
#pragma unroll
    for (int m = 0; m < 4; m++)
#pragma unroll
      for (int n = 0; n < 4; n++)
        acc[m][n] = __builtin_amdgcn_mfma_f32_16x16x32_bf16(af[m], bfr[n], acc[m][n], 0, 0, 0);
  }
  const int orow = (lane >> 4) * 4, ocol = lane & 15;
#pragma unroll
  for (int m = 0; m < 4; m++)
#pragma unroll
    for (int n = 0; n < 4; n++)
#pragma unroll
      for (int r = 0; r < 4; r++) {
        int gr = m0 + wm + m * 16 + orow + r;
        int gc = n0 + wn + n * 16 + ocol;
        if (OUT_F32) ((float*)C)[(size_t)gr * N + gc] = acc[m][n][r];
        else         ((short*)C)[(size_t)gr * N + gc] = f2bf(acc[m][n][r]);
      }
}

// ---------------- fused RoPE(Q,K) + V transpose/permute, one launch ----------------
// blockIdx.x < 32: RoPE on 64 s-rows. blockIdx.x >= 32: V -> Vt (BH, hd, S) with the
// in-block slot permutation p = c*32+g*8+4*hi+lo <- kv = c*32+hi*16+g*4+lo, so the attn
// PV A-fragment is one contiguous b128 read at [d][c*32+g*8].
__global__ __launch_bounds__(256) void ropev_kernel(
    const short* __restrict__ qkv, const float* __restrict__ ct, const float* __restrict__ st,
    short* __restrict__ Q, short* __restrict__ K, short* __restrict__ Vt) {
  int bh = blockIdx.y;
  int b = bh >> 4, h = bh & 15;
  int t = threadIdx.x;
  if (blockIdx.x < SS / 64) {
    int s0 = blockIdx.x * 64;
    int rl = t >> 2;
    int d8 = (t & 3) * 8;
    int s = s0 + rl;
    size_t inbase = ((size_t)(b * SS + s)) * 3072 + h * 64 + d8;
    size_t outbase = ((size_t)bh * SS + s) * 64 + d8;
    float c[8], sn[8];
#pragma unroll
    for (int j = 0; j < 8; j++) { c[j] = ct[s * 32 + d8 + j]; sn[j] = st[s * 32 + d8 + j]; }
    {
      bf16x8 x1 = *(const bf16x8*)(qkv + inbase);
      bf16x8 x2 = *(const bf16x8*)(qkv + inbase + 32);
      bf16x8 o1, o2;
#pragma unroll
      for (int j = 0; j < 8; j++) {
        float a = bf2f(x1[j]), bb = bf2f(x2[j]);
        o1[j] = f2bf((a * c[j] - bb * sn[j]) * QSCALE);
        o2[j] = f2bf((bb * c[j] + a * sn[j]) * QSCALE);
      }
      *(bf16x8*)(Q + outbase) = o1;
      *(bf16x8*)(Q + outbase + 32) = o2;
    }
    {
      bf16x8 x1 = *(const bf16x8*)(qkv + inbase + 1024);
      bf16x8 x2 = *(const bf16x8*)(qkv + inbase + 1024 + 32);
      bf16x8 o1, o2;
#pragma unroll
      for (int j = 0; j < 8; j++) {
        float a = bf2f(x1[j]), bb = bf2f(x2[j]);
        o1[j] = f2bf(a * c[j] - bb * sn[j]);
        o2[j] = f2bf(bb * c[j] + a * sn[j]);
      }
      *(bf16x8*)(K + outbase) = o1;
      *(bf16x8*)(K + outbase + 32) = o2;
    }
  } else {
    __shared__ short ls[64][72];
    int s0 = (blockIdx.x - SS / 64) * 64;
#pragma unroll
    for (int p = 0; p < 2; p++) {
      int idx = p * 256 + t;
      int r = idx >> 3, c8 = (idx & 7) * 8;
      *(bf16x8*)(&ls[r][c8]) =
          *(const bf16x8*)(qkv + ((size_t)(b * SS + s0 + r)) * 3072 + 2048 + h * 64 + c8);
    }
    __syncthreads();
    int dl = t >> 2, sg = (t & 3) * 16;
    int c = sg >> 5, hi = (sg >> 4) & 1;
    short tmp[16];
#pragma unroll
    for (int j = 0; j < 16; j++) tmp[j] = ls[sg + j][dl];
    size_t rowbase = ((size_t)bh * 64 + dl) * SS + s0;
#pragma unroll
    for (int g = 0; g < 4; g++) {
      short4 o = { tmp[4 * g], tmp[4 * g + 1], tmp[4 * g + 2], tmp[4 * g + 3] };
      *(short4*)(Vt + rowbase + c * 32 + g * 8 + hi * 4) = o;
    }
  }
}

// ---------------- Flash attention, causal. Balanced pairs + double-buffered staging ----------------
// QBLK=64, 4 waves. Each block runs TWO q-tile segments: qt = 31-pr (heavy) then pr (light),
// total exactly 33 kv-tiles per block -> zero drain imbalance. Grid 512, XCD-chunked.
// Per kv-tile: issue next-tile global->reg loads, compute current from buf[cur]
// (QK^T / lane-local softmax / PV), reg->LDS into buf[cur^1], ONE __syncthreads().
// HBM latency hides under compute; barrier count halved vs round 4.
__global__ __launch_bounds__(256) void attn_kernel(
    const short* __restrict__ Qp, const short* __restrict__ Kp, const short* __restrict__ Vt,
    short* __restrict__ O) {
  __shared__ short Ks[2][64][72];     // [buf][kv][d]
  __shared__ short Vs[2][64][72];     // [buf][d][permuted kv]
  int flat = blockIdx.x;
  int wk = (flat & 7) * 64 + (flat >> 3);   // 4 bh per XCD (512%8==0, bijective)
  int bh = wk >> 4;
  int pr = wk & 15;                   // pair index: segments qt = 31-pr, pr
  int b = bh >> 4, h = bh & 15;
  int tid = threadIdx.x, lane = tid & 63, w = tid >> 6;
  int row = lane & 15, grp = lane >> 4;

  const int ksr = tid >> 3;           // 0..31
  const int ksc = (tid & 7) * 8;
  const short* Kbase = Kp + (size_t)bh * SS * 64;
  const short* Vbase = Vt + (size_t)bh * 64 * SS;

  bf16x8 kr0, kr1, vr0, vr1;          // staging regs (next tile)
  auto LOADT = [&](int kv0) {
    kr0 = *(const bf16x8*)(Kbase + (size_t)(kv0 + ksr) * 64 + ksc);
    kr1 = *(const bf16x8*)(Kbase + (size_t)(kv0 + 32 + ksr) * 64 + ksc);
    vr0 = *(const bf16x8*)(Vbase + (size_t)ksr * SS + kv0 + ksc);
    vr1 = *(const bf16x8*)(Vbase + (size_t)(32 + ksr) * SS + kv0 + ksc);
  };
  auto WRITET = [&](int bufi) {
    *(bf16x8*)(&Ks[bufi][ksr][ksc]) = kr0;
    *(bf16x8*)(&Ks[bufi][32 + ksr][ksc]) = kr1;
    *(bf16x8*)(&Vs[bufi][ksr][ksc]) = vr0;
    *(bf16x8*)(&Vs[bufi][32 + ksr][ksc]) = vr1;
  };

  int cur = 0;
  LOADT(0);
  WRITET(0);
  __syncthreads();

#pragma unroll 1
  for (int s = 0; s < 2; s++) {
    const int qt = s ? pr : 31 - pr;
    const int q0 = qt * 64;
    const int q = q0 + w * 16 + row;  // this lane's q row
    bf16x8 qf0, qf1;
    {
      size_t qb = ((size_t)bh * SS + q) * 64 + grp * 8;
      qf0 = *(const bf16x8*)(Qp + qb);
      qf1 = *(const bf16x8*)(Qp + qb + 32);
    }
    f32x4 acc[4];
#pragma unroll
    for (int d = 0; d < 4; d++) acc[d] = (f32x4){0.f, 0.f, 0.f, 0.f};
    float m = -1e30f, l = 0.f;

#pragma unroll 1
    for (int kt = 0; kt <= qt; kt++) {
      int kv0 = kt * 64;
      bool more = (kt < qt) || (s == 0);
      if (more) LOADT(kt < qt ? kv0 + 64 : 0);   // next tile (or next segment's tile 0)

      bool last = (kt == qt);
      float sv[4][4];
#pragma unroll
      for (int n = 0; n < 4; n++) {
        if (last && n > w) {               // kv block fully above diagonal for this wave
#pragma unroll
          for (int r = 0; r < 4; r++) sv[n][r] = -1e30f;
          continue;
        }
        f32x4 sf = (f32x4){0.f, 0.f, 0.f, 0.f};
        bf16x8 kf0 = *(const bf16x8*)(&Ks[cur][n * 16 + row][grp * 8]);
        bf16x8 kf1 = *(const bf16x8*)(&Ks[cur][n * 16 + row][grp * 8 + 32]);
        sf = __builtin_amdgcn_mfma_f32_16x16x32_bf16(kf0, qf0, sf, 0, 0, 0);
        sf = __builtin_amdgcn_mfma_f32_16x16x32_bf16(kf1, qf1, sf, 0, 0, 0);
#pragma unroll
        for (int r = 0; r < 4; r++) sv[n][r] = sf[r];    // exp2-domain (QSCALE folded)
      }
      if (last) {                          // element mask only on the diagonal tile
#pragma unroll
        for (int n = 0; n < 4; n++)
#pragma unroll
          for (int r = 0; r < 4; r++) {
            int kv = kv0 + n * 16 + grp * 4 + r;
            if (kv > q) sv[n][r] = -1e30f;
          }
      }
      float pmax = -1e30f;
#pragma unroll
      for (int n = 0; n < 4; n++)
#pragma unroll
        for (int r = 0; r < 4; r++) pmax = fmaxf(pmax, sv[n][r]);
      pmax = fmaxf(pmax, __shfl_xor(pmax, 16));
      pmax = fmaxf(pmax, __shfl_xor(pmax, 32));
      float mnew = fmaxf(m, pmax);
      float resc = __builtin_amdgcn_exp2f(m - mnew);
      m = mnew;
      float p[4][4];
      float psum = 0.f;
#pragma unroll
      for (int n = 0; n < 4; n++)
#pragma unroll
        for (int r = 0; r < 4; r++) {
          p[n][r] = __builtin_amdgcn_exp2f(sv[n][r] - m);
          psum += p[n][r];
        }
      psum += __shfl_xor(psum, 16);
      psum += __shfl_xor(psum, 32);
      l = l * resc + psum;
#pragma unroll
      for (int d = 0; d < 4; d++)
#pragma unroll
        for (int r = 0; r < 4; r++) acc[d][r] *= resc;
      // PV: O^T = mfma(V^T_frag, P_frag); slot j -> kv = c*32 + 16*(j>>2) + grp*4 + (j&3)
#pragma unroll
      for (int c = 0; c < 2; c++) {
        union { unsigned int u[4]; bf16x8 v; } pu;
        pu.u[0] = cvtpk_bf16(p[2 * c][0], p[2 * c][1]);
        pu.u[1] = cvtpk_bf16(p[2 * c][2], p[2 * c][3]);
        pu.u[2] = cvtpk_bf16(p[2 * c + 1][0], p[2 * c + 1][1]);
        pu.u[3] = cvtpk_bf16(p[2 * c + 1][2], p[2 * c + 1][3]);
#pragma unroll
        for (int dm = 0; dm < 4; dm++) {
          bf16x8 vf = *(const bf16x8*)(&Vs[cur][dm * 16 + row][c * 32 + grp * 8]);
          acc[dm] = __builtin_amdgcn_mfma_f32_16x16x32_bf16(vf, pu.v, acc[dm], 0, 0, 0);
        }
      }
      if (more) WRITET(cur ^ 1);           // compiler waits vmcnt per-dependency here
      __syncthreads();                     // single barrier per tile
      cur ^= 1;
    }
    // epilogue: lane holds q, d = dm*16+grp*4+r
    float linv = 1.0f / l;
    size_t ob = ((size_t)(b * SS + q)) * 1024 + h * 64 + grp * 4;
#pragma unroll
    for (int dm = 0; dm < 4; dm++) {
      union { unsigned int u[2]; short4 s4; } ou;
      ou.u[0] = cvtpk_bf16(acc[dm][0] * linv, acc[dm][1] * linv);
      ou.u[1] = cvtpk_bf16(acc[dm][2] * linv, acc[dm][3] * linv);
      *(short4*)(O + ob + dm * 16) = ou.s4;
    }
  }
}

extern "C" void kernel_launch(void* const* d_in, const int* in_sizes, int n_in,
                              void* d_out, int out_size, void* d_ws, size_t ws_size,
                              hipStream_t stream) {
  (void)in_sizes; (void)n_in; (void)out_size; (void)ws_size;
  const float* x     = (const float*)d_in[0];
  const float* w_qkv = (const float*)d_in[1];
  const float* w_out = (const float*)d_in[2];
  float* out = (float*)d_out;

  char* ws = (char*)d_ws;
  size_t off = 0;
  auto alloc = [&](size_t bytes) -> void* {
    void* p = ws + off;
    off += (bytes + 255) & ~(size_t)255;
    return p;
  };
  short* xb    = (short*)alloc((size_t)MTOT * DIM * 2);      // dead after GEMM1
  short* wqkvb = (short*)alloc((size_t)3072 * 1024 * 2);
  short* woutb = (short*)alloc((size_t)1024 * 1024 * 2);
  short* qkvb  = (short*)alloc((size_t)MTOT * 3072 * 2);
  short* Qb    = (short*)alloc((size_t)32 * SS * 64 * 2);
  short* Kb    = (short*)alloc((size_t)32 * SS * 64 * 2);
  short* Vtb   = (short*)alloc((size_t)32 * 64 * SS * 2);
  float* ct    = (float*)alloc((size_t)SS * 32 * 4);
  float* st    = (float*)alloc((size_t)SS * 32 * 4);
  short* attnb = xb;   // reuse: xb's last read is GEMM1, attnb written after (stream-ordered)

  cvt3_kernel<<<2048, 256, 0, stream>>>(x, xb, MTOT * DIM / 4,
                                        w_qkv, wqkvb, 3072 * 1024 / 4,
                                        w_out, woutb, 1024 * 1024 / 4);
  rope_table_kernel<<<SS * 32 / 256, 256, 0, stream>>>(ct, st);
  gemm_bt<false><<<(3072 / 128) * (MTOT / 128), 256, 0, stream>>>(xb, wqkvb, qkvb, MTOT, 3072, 1024);
  ropev_kernel<<<dim3(2 * SS / 64, 32), 256, 0, stream>>>(qkvb, ct, st, Qb, Kb, Vtb);
  attn_kernel<<<512, 256, 0, stream>>>(Qb, Kb, Vtb, attnb);
  gemm_bt<true><<<(1024 / 128) * (MTOT / 128), 256, 0, stream>>>(attnb, woutb, out, MTOT, 1024, 1024);
}